// Round 1
// baseline (3712.972 us; speedup 1.0000x reference)
//
#include <hip/hip_runtime.h>
#include <hip/hip_bf16.h>

// GCN link-prediction: 2x GCNConv(128->128) + edge dot scoring.
// Round 1: correctness-first. Atomic scatter aggregation; fp32 GEMM with W in LDS.

#define N_NODES 100000
#define N_EDGES 1000000
#define N_LABEL 200000
#define D_FEAT 128

// ---------------- degree / norm ----------------
__global__ void deg_init(float* deg) {
    int i = blockIdx.x * 256 + threadIdx.x;
    if (i < N_NODES) deg[i] = 1.0f;  // self-loop
}

__global__ void deg_accum(const int* __restrict__ dst, float* deg) {
    int e = blockIdx.x * 256 + threadIdx.x;
    if (e < N_EDGES) atomicAdd(&deg[dst[e]], 1.0f);
}

__global__ void deg_rsqrt(float* deg) {
    int i = blockIdx.x * 256 + threadIdx.x;
    if (i < N_NODES) deg[i] = rsqrtf(deg[i]);
}

// ---------------- GEMM: Y[nrows x 128] = X[nrows x 128] @ W[128 x 128] ----------------
#define GEMM_ROWS 64
__global__ __launch_bounds__(256) void gemm128(const float* __restrict__ X,
                                               const float* __restrict__ W,
                                               float* __restrict__ Y, int nrows) {
    __shared__ float Ws[128 * 128];
    __shared__ float Xs[GEMM_ROWS * 128];
    int t = threadIdx.x;
    // load W (16384 floats = 4096 float4)
    for (int i = t; i < 128 * 32; i += 256)
        ((float4*)Ws)[i] = ((const float4*)W)[i];
    int row0 = blockIdx.x * GEMM_ROWS;
    for (int i = t; i < GEMM_ROWS * 32; i += 256) {
        int r = row0 + (i >> 5);
        float4 v = make_float4(0.f, 0.f, 0.f, 0.f);
        if (r < nrows) v = ((const float4*)X)[r * 32 + (i & 31)];
        ((float4*)Xs)[i] = v;
    }
    __syncthreads();
    int c4 = t & 31;   // column group: cols c4*4 .. c4*4+3
    int rg = t >> 5;   // row group 0..7; handles rows rg, rg+8, ..., rg+56
    float4 acc[8];
#pragma unroll
    for (int i = 0; i < 8; ++i) acc[i] = make_float4(0.f, 0.f, 0.f, 0.f);
    for (int k = 0; k < 128; ++k) {
        float4 w = ((float4*)Ws)[k * 32 + c4];
#pragma unroll
        for (int i = 0; i < 8; ++i) {
            float xv = Xs[(rg + i * 8) * 128 + k];
            acc[i].x = fmaf(xv, w.x, acc[i].x);
            acc[i].y = fmaf(xv, w.y, acc[i].y);
            acc[i].z = fmaf(xv, w.z, acc[i].z);
            acc[i].w = fmaf(xv, w.w, acc[i].w);
        }
    }
#pragma unroll
    for (int i = 0; i < 8; ++i) {
        int r = row0 + rg + i * 8;
        if (r < nrows) ((float4*)Y)[r * 32 + c4] = acc[i];
    }
}

// ---------------- self-loop init: X[v] = dinv[v]^2 * H[v] ----------------
__global__ void selfloop_init(const float* __restrict__ H, const float* __restrict__ dinv,
                              float* __restrict__ X) {
    int i = blockIdx.x * 256 + threadIdx.x;  // over N_NODES*32 float4
    if (i >= N_NODES * 32) return;
    int v = i >> 5;
    float d2 = dinv[v] * dinv[v];
    float4 h = ((const float4*)H)[i];
    float4 r;
    r.x = d2 * h.x; r.y = d2 * h.y; r.z = d2 * h.z; r.w = d2 * h.w;
    ((float4*)X)[i] = r;
}

// ---------------- edge scatter: X[dst] += dinv[src]*dinv[dst]*H[src] ----------------
__global__ void scatter_edges(const int* __restrict__ src, const int* __restrict__ dst,
                              const float* __restrict__ dinv,
                              const float* __restrict__ H, float* __restrict__ X) {
    int tid = blockIdx.x * 256 + threadIdx.x;  // E*32 threads
    int e = tid >> 5, q = tid & 31;
    if (e >= N_EDGES) return;
    int s = src[e], d = dst[e];
    float norm = dinv[s] * dinv[d];
    float4 h = ((const float4*)H)[s * 32 + q];
    float* xp = X + (size_t)d * D_FEAT + q * 4;
    atomicAdd(xp + 0, norm * h.x);
    atomicAdd(xp + 1, norm * h.y);
    atomicAdd(xp + 2, norm * h.z);
    atomicAdd(xp + 3, norm * h.w);
}

// ---------------- bias + relu (layer 1 epilogue) ----------------
__global__ void relu_bias(float* __restrict__ X, const float* __restrict__ b) {
    int i = blockIdx.x * 256 + threadIdx.x;  // over N_NODES*32 float4
    if (i >= N_NODES * 32) return;
    float4 bb = ((const float4*)b)[i & 31];
    float4 x = ((float4*)X)[i];
    x.x = fmaxf(x.x + bb.x, 0.f);
    x.y = fmaxf(x.y + bb.y, 0.f);
    x.z = fmaxf(x.z + bb.z, 0.f);
    x.w = fmaxf(x.w + bb.w, 0.f);
    ((float4*)X)[i] = x;
}

// ---------------- edge scoring: out[e] = dot(X[a]+b2, X[b]+b2) ----------------
__global__ void score_kernel(const int* __restrict__ ea, const int* __restrict__ eb,
                             const float* __restrict__ X, const float* __restrict__ bias,
                             float* __restrict__ out) {
    int gt = blockIdx.x * 256 + threadIdx.x;
    int wid = gt >> 6;
    int lane = gt & 63;
    if (wid >= N_LABEL) return;
    int ia = ea[wid], ib = eb[wid];
    float2 ba = ((const float2*)bias)[lane];
    float2 xa = ((const float2*)(X + (size_t)ia * D_FEAT))[lane];
    float2 xb = ((const float2*)(X + (size_t)ib * D_FEAT))[lane];
    float p = (xa.x + ba.x) * (xb.x + ba.x) + (xa.y + ba.y) * (xb.y + ba.y);
#pragma unroll
    for (int off = 32; off > 0; off >>= 1) p += __shfl_down(p, off);
    if (lane == 0) out[wid] = p;
}

extern "C" void kernel_launch(void* const* d_in, const int* in_sizes, int n_in,
                              void* d_out, int out_size, void* d_ws, size_t ws_size,
                              hipStream_t stream) {
    const float* feat = (const float*)d_in[0];
    const int* ei = (const int*)d_in[1];      // [2, E]: row0=src, row1=dst
    const int* eli = (const int*)d_in[2];     // [2, L]
    const float* W1 = (const float*)d_in[3];
    const float* b1 = (const float*)d_in[4];
    const float* W2 = (const float*)d_in[5];
    const float* b2 = (const float*)d_in[6];
    float* out = (float*)d_out;

    const int* src = ei;
    const int* dst = ei + N_EDGES;
    const int* la = eli;
    const int* lb = eli + N_LABEL;

    float* ws = (float*)d_ws;
    float* dinv = ws;                       // N floats
    float* H = ws + N_NODES;                // N*128 floats
    float* X = H + (size_t)N_NODES * 128;   // N*128 floats

    const int TB = 256;
    int gN = (N_NODES + TB - 1) / TB;
    int gE = (N_EDGES + TB - 1) / TB;
    int gNF4 = (N_NODES * 32 + TB - 1) / TB;       // N*32 float4 threads
    int gES = (N_EDGES * 32 + TB - 1) / TB;        // E*32 scatter threads
    int gGemm = (N_NODES + GEMM_ROWS - 1) / GEMM_ROWS;
    int gScore = (N_LABEL * 64 + TB - 1) / TB;

    // degree + rsqrt
    deg_init<<<gN, TB, 0, stream>>>(dinv);
    deg_accum<<<gE, TB, 0, stream>>>(dst, dinv);
    deg_rsqrt<<<gN, TB, 0, stream>>>(dinv);

    // layer 1
    gemm128<<<gGemm, TB, 0, stream>>>(feat, W1, H, N_NODES);
    selfloop_init<<<gNF4, TB, 0, stream>>>(H, dinv, X);
    scatter_edges<<<gES, TB, 0, stream>>>(src, dst, dinv, H, X);
    relu_bias<<<gNF4, TB, 0, stream>>>(X, b1);

    // layer 2 (reuse H; X overwritten after transform)
    gemm128<<<gGemm, TB, 0, stream>>>(X, W2, H, N_NODES);
    selfloop_init<<<gNF4, TB, 0, stream>>>(H, dinv, X);
    scatter_edges<<<gES, TB, 0, stream>>>(src, dst, dinv, H, X);

    // scoring (b2 folded in)
    score_kernel<<<gScore, TB, 0, stream>>>(la, lb, X, b2, out);
}

// Round 2
// 614.430 us; speedup vs baseline: 6.0430x; 6.0430x over previous
//
#include <hip/hip_runtime.h>
#include <hip/hip_bf16.h>

// GCN link-prediction: 2x GCNConv(128->128) + edge dot scoring.
// Round 2: replace fp32 atomic scatter (2x1650us) with on-device CSR build +
// register gather-reduce per node. Norm precomputed once, packed {col, norm}.

#define N_NODES 100000
#define N_EDGES 1000000
#define N_LABEL 200000
#define D_FEAT 128

// ---------------- degree histogram (int atomics) ----------------
__global__ void deg_hist(const int* __restrict__ dst, int* __restrict__ counts) {
    int e = blockIdx.x * 256 + threadIdx.x;
    if (e < N_EDGES) atomicAdd(&counts[dst[e]], 1);
}

__global__ void make_dinv(const int* __restrict__ counts, float* __restrict__ dinv) {
    int i = blockIdx.x * 256 + threadIdx.x;
    if (i < N_NODES) dinv[i] = rsqrtf((float)(counts[i] + 1));  // +1 self-loop
}

// ---------------- exclusive scan over counts -> row_ptr ----------------
// 1024 elements per block, 256 threads x 4.
__global__ __launch_bounds__(256) void scan_reduce(const int* __restrict__ counts,
                                                   int* __restrict__ bsums) {
    __shared__ int s[256];
    int t = threadIdx.x;
    int base = blockIdx.x * 1024 + t * 4;
    int sum = 0;
#pragma unroll
    for (int j = 0; j < 4; ++j) {
        int idx = base + j;
        if (idx < N_NODES) sum += counts[idx];
    }
    s[t] = sum;
    __syncthreads();
    for (int off = 128; off > 0; off >>= 1) {
        if (t < off) s[t] += s[t + off];
        __syncthreads();
    }
    if (t == 0) bsums[blockIdx.x] = s[0];
}

__global__ void scan_top(int* __restrict__ bsums, int nb) {
    __shared__ int s[128];
    int t = threadIdx.x;
    s[t] = (t < nb) ? bsums[t] : 0;
    __syncthreads();
    for (int off = 1; off < 128; off <<= 1) {
        int v = (t >= off) ? s[t - off] : 0;
        __syncthreads();
        s[t] += v;
        __syncthreads();
    }
    if (t < nb) bsums[t] = (t == 0) ? 0 : s[t - 1];
}

__global__ __launch_bounds__(256) void scan_apply(const int* __restrict__ counts,
                                                  const int* __restrict__ bsums,
                                                  int* __restrict__ row_ptr) {
    __shared__ int s[256];
    int t = threadIdx.x;
    int base = blockIdx.x * 1024 + t * 4;
    int v[4];
    int sum = 0;
#pragma unroll
    for (int j = 0; j < 4; ++j) {
        int idx = base + j;
        v[j] = (idx < N_NODES) ? counts[idx] : 0;
        sum += v[j];
    }
    s[t] = sum;
    __syncthreads();
    for (int off = 1; off < 256; off <<= 1) {
        int a = (t >= off) ? s[t - off] : 0;
        __syncthreads();
        s[t] += a;
        __syncthreads();
    }
    int excl = ((t == 0) ? 0 : s[t - 1]) + bsums[blockIdx.x];
    int run = 0;
#pragma unroll
    for (int j = 0; j < 4; ++j) {
        int idx = base + j;
        if (idx < N_NODES) row_ptr[idx] = excl + run;
        run += v[j];
    }
    if (blockIdx.x == 0 && t == 0) row_ptr[N_NODES] = N_EDGES;
}

// ---------------- bucket fill: packed[pos] = {src, norm} ----------------
__global__ void fill_csr(const int* __restrict__ src, const int* __restrict__ dst,
                         const float* __restrict__ dinv, const int* __restrict__ row_ptr,
                         int* __restrict__ fill, int2* __restrict__ packed) {
    int e = blockIdx.x * 256 + threadIdx.x;
    if (e >= N_EDGES) return;
    int s = src[e], d = dst[e];
    int pos = row_ptr[d] + atomicAdd(&fill[d], 1);
    float norm = dinv[s] * dinv[d];
    packed[pos] = make_int2(s, __float_as_int(norm));
}

// ---------------- GEMM: Y[nrows x 128] = X[nrows x 128] @ W[128 x 128] ----------------
#define GEMM_ROWS 64
__global__ __launch_bounds__(256) void gemm128(const float* __restrict__ X,
                                               const float* __restrict__ W,
                                               float* __restrict__ Y, int nrows) {
    __shared__ float Ws[128 * 128];
    __shared__ float Xs[GEMM_ROWS * 128];
    int t = threadIdx.x;
    for (int i = t; i < 128 * 32; i += 256)
        ((float4*)Ws)[i] = ((const float4*)W)[i];
    int row0 = blockIdx.x * GEMM_ROWS;
    for (int i = t; i < GEMM_ROWS * 32; i += 256) {
        int r = row0 + (i >> 5);
        float4 v = make_float4(0.f, 0.f, 0.f, 0.f);
        if (r < nrows) v = ((const float4*)X)[r * 32 + (i & 31)];
        ((float4*)Xs)[i] = v;
    }
    __syncthreads();
    int c4 = t & 31;
    int rg = t >> 5;
    float4 acc[8];
#pragma unroll
    for (int i = 0; i < 8; ++i) acc[i] = make_float4(0.f, 0.f, 0.f, 0.f);
    for (int k = 0; k < 128; ++k) {
        float4 w = ((float4*)Ws)[k * 32 + c4];
#pragma unroll
        for (int i = 0; i < 8; ++i) {
            float xv = Xs[(rg + i * 8) * 128 + k];
            acc[i].x = fmaf(xv, w.x, acc[i].x);
            acc[i].y = fmaf(xv, w.y, acc[i].y);
            acc[i].z = fmaf(xv, w.z, acc[i].z);
            acc[i].w = fmaf(xv, w.w, acc[i].w);
        }
    }
#pragma unroll
    for (int i = 0; i < 8; ++i) {
        int r = row0 + rg + i * 8;
        if (r < nrows) ((float4*)Y)[r * 32 + c4] = acc[i];
    }
}

// ---------------- gather-aggregate per node ----------------
// 32 lanes/node, float4/lane. X[v] = [relu](d2*H[v] + sum norm*H[col] [+ b])
template <bool RELU>
__global__ __launch_bounds__(256) void aggregate(const float* __restrict__ H,
                                                 const int2* __restrict__ packed,
                                                 const int* __restrict__ row_ptr,
                                                 const float* __restrict__ dinv,
                                                 const float* __restrict__ bias,
                                                 float* __restrict__ X) {
    int v = blockIdx.x * 8 + (threadIdx.x >> 5);
    int q = threadIdx.x & 31;
    if (v >= N_NODES) return;
    int start = row_ptr[v];
    int end = row_ptr[v + 1];
    float dv = dinv[v];
    float d2 = dv * dv;
    float4 h0 = ((const float4*)H)[v * 32 + q];
    float4 acc;
    acc.x = d2 * h0.x; acc.y = d2 * h0.y; acc.z = d2 * h0.z; acc.w = d2 * h0.w;
    for (int i = start; i < end; ++i) {
        int2 p = packed[i];
        float nrm = __int_as_float(p.y);
        float4 h = ((const float4*)H)[p.x * 32 + q];
        acc.x = fmaf(nrm, h.x, acc.x);
        acc.y = fmaf(nrm, h.y, acc.y);
        acc.z = fmaf(nrm, h.z, acc.z);
        acc.w = fmaf(nrm, h.w, acc.w);
    }
    if (RELU) {
        float4 b = ((const float4*)bias)[q];
        acc.x = fmaxf(acc.x + b.x, 0.f);
        acc.y = fmaxf(acc.y + b.y, 0.f);
        acc.z = fmaxf(acc.z + b.z, 0.f);
        acc.w = fmaxf(acc.w + b.w, 0.f);
    }
    ((float4*)X)[v * 32 + q] = acc;
}

// ---------------- edge scoring: out[e] = dot(X[a]+b2, X[b]+b2) ----------------
__global__ void score_kernel(const int* __restrict__ ea, const int* __restrict__ eb,
                             const float* __restrict__ X, const float* __restrict__ bias,
                             float* __restrict__ out) {
    int gt = blockIdx.x * 256 + threadIdx.x;
    int wid = gt >> 6;
    int lane = gt & 63;
    if (wid >= N_LABEL) return;
    int ia = ea[wid], ib = eb[wid];
    float2 ba = ((const float2*)bias)[lane];
    float2 xa = ((const float2*)(X + (size_t)ia * D_FEAT))[lane];
    float2 xb = ((const float2*)(X + (size_t)ib * D_FEAT))[lane];
    float p = (xa.x + ba.x) * (xb.x + ba.x) + (xa.y + ba.y) * (xb.y + ba.y);
#pragma unroll
    for (int off = 32; off > 0; off >>= 1) p += __shfl_down(p, off);
    if (lane == 0) out[wid] = p;
}

extern "C" void kernel_launch(void* const* d_in, const int* in_sizes, int n_in,
                              void* d_out, int out_size, void* d_ws, size_t ws_size,
                              hipStream_t stream) {
    const float* feat = (const float*)d_in[0];
    const int* ei = (const int*)d_in[1];
    const int* eli = (const int*)d_in[2];
    const float* W1 = (const float*)d_in[3];
    const float* b1 = (const float*)d_in[4];
    const float* W2 = (const float*)d_in[5];
    const float* b2 = (const float*)d_in[6];
    float* out = (float*)d_out;

    const int* src = ei;
    const int* dst = ei + N_EDGES;
    const int* la = eli;
    const int* lb = eli + N_LABEL;

    // ---- workspace layout (16B-aligned sections) ----
    int* counts = (int*)d_ws;                    // N
    int* fill = counts + N_NODES;                // N
    int* row_ptr = fill + N_NODES;               // N+1
    int* bsums = row_ptr + N_NODES + 1;          // 128
    float* dinv = (float*)(bsums + 128);         // N
    // pad to 16B: ints so far = 4*N + 129; pad 3 -> 4*N + 132 (mult of 4)
    int2* packed = (int2*)(dinv + N_NODES + 3);  // E int2 (8 MB)
    float* H = (float*)(packed + N_EDGES);       // N*128
    float* X = H + (size_t)N_NODES * 128;        // N*128

    const int TB = 256;
    int gE = (N_EDGES + TB - 1) / TB;
    int gN = (N_NODES + TB - 1) / TB;
    int gScan = (N_NODES + 1023) / 1024;                 // 98
    int gGemm = (N_NODES + GEMM_ROWS - 1) / GEMM_ROWS;   // 1563
    int gAgg = (N_NODES + 7) / 8;                        // 12500
    int gScore = (N_LABEL * 64 + TB - 1) / TB;           // 50000

    // zero counts + fill (adjacent, one memset)
    hipMemsetAsync(counts, 0, 2 * N_NODES * sizeof(int), stream);

    // CSR build
    deg_hist<<<gE, TB, 0, stream>>>(dst, counts);
    make_dinv<<<gN, TB, 0, stream>>>(counts, dinv);
    scan_reduce<<<gScan, TB, 0, stream>>>(counts, bsums);
    scan_top<<<1, 128, 0, stream>>>(bsums, gScan);
    scan_apply<<<gScan, TB, 0, stream>>>(counts, bsums, row_ptr);
    fill_csr<<<gE, TB, 0, stream>>>(src, dst, dinv, row_ptr, fill, packed);

    // layer 1
    gemm128<<<gGemm, TB, 0, stream>>>(feat, W1, H, N_NODES);
    aggregate<true><<<gAgg, TB, 0, stream>>>(H, packed, row_ptr, dinv, b1, X);

    // layer 2
    gemm128<<<gGemm, TB, 0, stream>>>(X, W2, H, N_NODES);
    aggregate<false><<<gAgg, TB, 0, stream>>>(H, packed, row_ptr, dinv, b2, X);

    // scoring (b2 folded in)
    score_kernel<<<gScore, TB, 0, stream>>>(la, lb, X, b2, out);
}

// Round 3
// 553.613 us; speedup vs baseline: 6.7068x; 1.1099x over previous
//
#include <hip/hip_runtime.h>
#include <hip/hip_bf16.h>

// GCN link-prediction: 2x GCNConv(128->128) + edge dot scoring.
// Round 3: GEMM restructure. 128x128 block tile, 8x8 per-thread micro-tile,
// BK=32 chunks (LDS 35KB -> multi-block/CU), XOR-swizzled Xs (bank-conflict-free).

#define N_NODES 100000
#define N_EDGES 1000000
#define N_LABEL 200000
#define D_FEAT 128

// ---------------- degree histogram (int atomics) ----------------
__global__ void deg_hist(const int* __restrict__ dst, int* __restrict__ counts) {
    int e = blockIdx.x * 256 + threadIdx.x;
    if (e < N_EDGES) atomicAdd(&counts[dst[e]], 1);
}

__global__ void make_dinv(const int* __restrict__ counts, float* __restrict__ dinv) {
    int i = blockIdx.x * 256 + threadIdx.x;
    if (i < N_NODES) dinv[i] = rsqrtf((float)(counts[i] + 1));  // +1 self-loop
}

// ---------------- exclusive scan over counts -> row_ptr ----------------
__global__ __launch_bounds__(256) void scan_reduce(const int* __restrict__ counts,
                                                   int* __restrict__ bsums) {
    __shared__ int s[256];
    int t = threadIdx.x;
    int base = blockIdx.x * 1024 + t * 4;
    int sum = 0;
#pragma unroll
    for (int j = 0; j < 4; ++j) {
        int idx = base + j;
        if (idx < N_NODES) sum += counts[idx];
    }
    s[t] = sum;
    __syncthreads();
    for (int off = 128; off > 0; off >>= 1) {
        if (t < off) s[t] += s[t + off];
        __syncthreads();
    }
    if (t == 0) bsums[blockIdx.x] = s[0];
}

__global__ void scan_top(int* __restrict__ bsums, int nb) {
    __shared__ int s[128];
    int t = threadIdx.x;
    s[t] = (t < nb) ? bsums[t] : 0;
    __syncthreads();
    for (int off = 1; off < 128; off <<= 1) {
        int v = (t >= off) ? s[t - off] : 0;
        __syncthreads();
        s[t] += v;
        __syncthreads();
    }
    if (t < nb) bsums[t] = (t == 0) ? 0 : s[t - 1];
}

__global__ __launch_bounds__(256) void scan_apply(const int* __restrict__ counts,
                                                  const int* __restrict__ bsums,
                                                  int* __restrict__ row_ptr) {
    __shared__ int s[256];
    int t = threadIdx.x;
    int base = blockIdx.x * 1024 + t * 4;
    int v[4];
    int sum = 0;
#pragma unroll
    for (int j = 0; j < 4; ++j) {
        int idx = base + j;
        v[j] = (idx < N_NODES) ? counts[idx] : 0;
        sum += v[j];
    }
    s[t] = sum;
    __syncthreads();
    for (int off = 1; off < 256; off <<= 1) {
        int a = (t >= off) ? s[t - off] : 0;
        __syncthreads();
        s[t] += a;
        __syncthreads();
    }
    int excl = ((t == 0) ? 0 : s[t - 1]) + bsums[blockIdx.x];
    int run = 0;
#pragma unroll
    for (int j = 0; j < 4; ++j) {
        int idx = base + j;
        if (idx < N_NODES) row_ptr[idx] = excl + run;
        run += v[j];
    }
    if (blockIdx.x == 0 && t == 0) row_ptr[N_NODES] = N_EDGES;
}

// ---------------- bucket fill: packed[pos] = {src, norm} ----------------
__global__ void fill_csr(const int* __restrict__ src, const int* __restrict__ dst,
                         const float* __restrict__ dinv, const int* __restrict__ row_ptr,
                         int* __restrict__ fill, int2* __restrict__ packed) {
    int e = blockIdx.x * 256 + threadIdx.x;
    if (e >= N_EDGES) return;
    int s = src[e], d = dst[e];
    int pos = row_ptr[d] + atomicAdd(&fill[d], 1);
    float norm = dinv[s] * dinv[d];
    packed[pos] = make_int2(s, __float_as_int(norm));
}

// ---------------- GEMM: Y[nrows x 128] = X[nrows x 128] @ W[128 x 128] ----------------
// 128x128 tile, 256 threads, 8x8 per thread, K chunked by 32.
#define BM 128
#define BK 32
// Xs: swizzled [row][f4-group]: group g of row r stored at ((g + (r>>3)) & 7)
#define XS_STRIDE 36  // 8 f4 groups + 1 pad group (keeps 16B align, spreads banks)
__global__ __launch_bounds__(256) void gemm128(const float* __restrict__ X,
                                               const float* __restrict__ W,
                                               float* __restrict__ Y, int nrows) {
    __shared__ float Xs[BM * XS_STRIDE];       // 18432 B
    __shared__ float Ws[BK * 132];             // 16896 B
    int t = threadIdx.x;
    int tcg = t & 15;        // col group: cols tcg*8 .. +7
    int trg = t >> 4;        // row group: rows trg*8 .. +7
    int row0 = blockIdx.x * BM;

    float acc[8][8];
#pragma unroll
    for (int r = 0; r < 8; ++r)
#pragma unroll
        for (int c = 0; c < 8; ++c) acc[r][c] = 0.f;

    for (int k0 = 0; k0 < 128; k0 += BK) {
        // stage X: 128 rows x 32 k = 1024 float4, swizzled
        for (int i = t; i < 1024; i += 256) {
            int r = i >> 3, g = i & 7;
            float4 v = make_float4(0.f, 0.f, 0.f, 0.f);
            if (row0 + r < nrows)
                v = ((const float4*)X)[(size_t)(row0 + r) * 32 + (k0 >> 2) + g];
            int gs = (g + (r >> 3)) & 7;
            *(float4*)&Xs[r * XS_STRIDE + gs * 4] = v;
        }
        // stage W: 32 k x 128 c = 1024 float4
        for (int i = t; i < 1024; i += 256) {
            int kk = i >> 5, c4 = i & 31;
            *(float4*)&Ws[kk * 132 + c4 * 4] =
                ((const float4*)W)[(size_t)(k0 + kk) * 32 + c4];
        }
        __syncthreads();

#pragma unroll
        for (int kk = 0; kk < BK; kk += 4) {
            float4 xv[8];
#pragma unroll
            for (int r = 0; r < 8; ++r) {
                int gs = ((kk >> 2) + trg) & 7;
                xv[r] = *(float4*)&Xs[(trg * 8 + r) * XS_STRIDE + gs * 4];
            }
#pragma unroll
            for (int j = 0; j < 4; ++j) {
                float4 wa = *(float4*)&Ws[(kk + j) * 132 + tcg * 8];
                float4 wb = *(float4*)&Ws[(kk + j) * 132 + tcg * 8 + 4];
#pragma unroll
                for (int r = 0; r < 8; ++r) {
                    float xr = j == 0 ? xv[r].x : j == 1 ? xv[r].y : j == 2 ? xv[r].z : xv[r].w;
                    acc[r][0] = fmaf(xr, wa.x, acc[r][0]);
                    acc[r][1] = fmaf(xr, wa.y, acc[r][1]);
                    acc[r][2] = fmaf(xr, wa.z, acc[r][2]);
                    acc[r][3] = fmaf(xr, wa.w, acc[r][3]);
                    acc[r][4] = fmaf(xr, wb.x, acc[r][4]);
                    acc[r][5] = fmaf(xr, wb.y, acc[r][5]);
                    acc[r][6] = fmaf(xr, wb.z, acc[r][6]);
                    acc[r][7] = fmaf(xr, wb.w, acc[r][7]);
                }
            }
        }
        __syncthreads();
    }

#pragma unroll
    for (int r = 0; r < 8; ++r) {
        int row = row0 + trg * 8 + r;
        if (row < nrows) {
            float4 a = make_float4(acc[r][0], acc[r][1], acc[r][2], acc[r][3]);
            float4 b = make_float4(acc[r][4], acc[r][5], acc[r][6], acc[r][7]);
            ((float4*)Y)[(size_t)row * 32 + tcg * 2] = a;
            ((float4*)Y)[(size_t)row * 32 + tcg * 2 + 1] = b;
        }
    }
}

// ---------------- gather-aggregate per node ----------------
template <bool RELU>
__global__ __launch_bounds__(256) void aggregate(const float* __restrict__ H,
                                                 const int2* __restrict__ packed,
                                                 const int* __restrict__ row_ptr,
                                                 const float* __restrict__ dinv,
                                                 const float* __restrict__ bias,
                                                 float* __restrict__ X) {
    int v = blockIdx.x * 8 + (threadIdx.x >> 5);
    int q = threadIdx.x & 31;
    if (v >= N_NODES) return;
    int start = row_ptr[v];
    int end = row_ptr[v + 1];
    float dv = dinv[v];
    float d2 = dv * dv;
    float4 h0 = ((const float4*)H)[v * 32 + q];
    float4 acc;
    acc.x = d2 * h0.x; acc.y = d2 * h0.y; acc.z = d2 * h0.z; acc.w = d2 * h0.w;
    for (int i = start; i < end; ++i) {
        int2 p = packed[i];
        float nrm = __int_as_float(p.y);
        float4 h = ((const float4*)H)[p.x * 32 + q];
        acc.x = fmaf(nrm, h.x, acc.x);
        acc.y = fmaf(nrm, h.y, acc.y);
        acc.z = fmaf(nrm, h.z, acc.z);
        acc.w = fmaf(nrm, h.w, acc.w);
    }
    if (RELU) {
        float4 b = ((const float4*)bias)[q];
        acc.x = fmaxf(acc.x + b.x, 0.f);
        acc.y = fmaxf(acc.y + b.y, 0.f);
        acc.z = fmaxf(acc.z + b.z, 0.f);
        acc.w = fmaxf(acc.w + b.w, 0.f);
    }
    ((float4*)X)[v * 32 + q] = acc;
}

// ---------------- edge scoring: out[e] = dot(X[a]+b2, X[b]+b2) ----------------
__global__ void score_kernel(const int* __restrict__ ea, const int* __restrict__ eb,
                             const float* __restrict__ X, const float* __restrict__ bias,
                             float* __restrict__ out) {
    int gt = blockIdx.x * 256 + threadIdx.x;
    int wid = gt >> 6;
    int lane = gt & 63;
    if (wid >= N_LABEL) return;
    int ia = ea[wid], ib = eb[wid];
    float2 ba = ((const float2*)bias)[lane];
    float2 xa = ((const float2*)(X + (size_t)ia * D_FEAT))[lane];
    float2 xb = ((const float2*)(X + (size_t)ib * D_FEAT))[lane];
    float p = (xa.x + ba.x) * (xb.x + ba.x) + (xa.y + ba.y) * (xb.y + ba.y);
#pragma unroll
    for (int off = 32; off > 0; off >>= 1) p += __shfl_down(p, off);
    if (lane == 0) out[wid] = p;
}

extern "C" void kernel_launch(void* const* d_in, const int* in_sizes, int n_in,
                              void* d_out, int out_size, void* d_ws, size_t ws_size,
                              hipStream_t stream) {
    const float* feat = (const float*)d_in[0];
    const int* ei = (const int*)d_in[1];
    const int* eli = (const int*)d_in[2];
    const float* W1 = (const float*)d_in[3];
    const float* b1 = (const float*)d_in[4];
    const float* W2 = (const float*)d_in[5];
    const float* b2 = (const float*)d_in[6];
    float* out = (float*)d_out;

    const int* src = ei;
    const int* dst = ei + N_EDGES;
    const int* la = eli;
    const int* lb = eli + N_LABEL;

    int* counts = (int*)d_ws;                    // N
    int* fill = counts + N_NODES;                // N
    int* row_ptr = fill + N_NODES;               // N+1
    int* bsums = row_ptr + N_NODES + 1;          // 128
    float* dinv = (float*)(bsums + 128);         // N
    int2* packed = (int2*)(dinv + N_NODES + 3);  // E int2 (8 MB)
    float* H = (float*)(packed + N_EDGES);       // N*128
    float* X = H + (size_t)N_NODES * 128;        // N*128

    const int TB = 256;
    int gE = (N_EDGES + TB - 1) / TB;
    int gN = (N_NODES + TB - 1) / TB;
    int gScan = (N_NODES + 1023) / 1024;
    int gGemm = (N_NODES + BM - 1) / BM;                 // 782
    int gAgg = (N_NODES + 7) / 8;
    int gScore = (N_LABEL * 64 + TB - 1) / TB;

    hipMemsetAsync(counts, 0, 2 * N_NODES * sizeof(int), stream);

    // CSR build
    deg_hist<<<gE, TB, 0, stream>>>(dst, counts);
    make_dinv<<<gN, TB, 0, stream>>>(counts, dinv);
    scan_reduce<<<gScan, TB, 0, stream>>>(counts, bsums);
    scan_top<<<1, 128, 0, stream>>>(bsums, gScan);
    scan_apply<<<gScan, TB, 0, stream>>>(counts, bsums, row_ptr);
    fill_csr<<<gE, TB, 0, stream>>>(src, dst, dinv, row_ptr, fill, packed);

    // layer 1
    gemm128<<<gGemm, TB, 0, stream>>>(feat, W1, H, N_NODES);
    aggregate<true><<<gAgg, TB, 0, stream>>>(H, packed, row_ptr, dinv, b1, X);

    // layer 2
    gemm128<<<gGemm, TB, 0, stream>>>(X, W2, H, N_NODES);
    aggregate<false><<<gAgg, TB, 0, stream>>>(H, packed, row_ptr, dinv, b2, X);

    // scoring (b2 folded in)
    score_kernel<<<gScore, TB, 0, stream>>>(la, lb, X, b2, out);
}

// Round 4
// 499.540 us; speedup vs baseline: 7.4328x; 1.1082x over previous
//
#include <hip/hip_runtime.h>
#include <hip/hip_bf16.h>

// GCN link-prediction: 2x GCNConv(128->128) + edge dot scoring.
// Round 4: bf16 intermediate features (halves gather/store traffic in the
// traffic-bound aggregate + score), wave-per-node aggregate with lane-parallel
// edge fetch + shfl broadcast. GEMM keeps fp32 accumulate, bf16 I/O.

#define N_NODES 100000
#define N_EDGES 1000000
#define N_LABEL 200000
#define D_FEAT 128

// ---- bf16 helpers (RNE) ----
__device__ inline unsigned int f2bf(float x) {
    unsigned int u = __float_as_uint(x);
    return (u + 0x7FFFu + ((u >> 16) & 1u)) >> 16;
}
__device__ inline unsigned int bf16pack(float a, float b) {
    return f2bf(a) | (f2bf(b) << 16);
}
__device__ inline float bflo(unsigned int u) { return __uint_as_float(u << 16); }
__device__ inline float bfhi(unsigned int u) { return __uint_as_float(u & 0xFFFF0000u); }

// ---------------- degree histogram (int atomics) ----------------
__global__ void deg_hist(const int* __restrict__ dst, int* __restrict__ counts) {
    int e = blockIdx.x * 256 + threadIdx.x;
    if (e < N_EDGES) atomicAdd(&counts[dst[e]], 1);
}

__global__ void make_dinv(const int* __restrict__ counts, float* __restrict__ dinv) {
    int i = blockIdx.x * 256 + threadIdx.x;
    if (i < N_NODES) dinv[i] = rsqrtf((float)(counts[i] + 1));  // +1 self-loop
}

// ---------------- exclusive scan over counts -> row_ptr ----------------
__global__ __launch_bounds__(256) void scan_reduce(const int* __restrict__ counts,
                                                   int* __restrict__ bsums) {
    __shared__ int s[256];
    int t = threadIdx.x;
    int base = blockIdx.x * 1024 + t * 4;
    int sum = 0;
#pragma unroll
    for (int j = 0; j < 4; ++j) {
        int idx = base + j;
        if (idx < N_NODES) sum += counts[idx];
    }
    s[t] = sum;
    __syncthreads();
    for (int off = 128; off > 0; off >>= 1) {
        if (t < off) s[t] += s[t + off];
        __syncthreads();
    }
    if (t == 0) bsums[blockIdx.x] = s[0];
}

__global__ void scan_top(int* __restrict__ bsums, int nb) {
    __shared__ int s[128];
    int t = threadIdx.x;
    s[t] = (t < nb) ? bsums[t] : 0;
    __syncthreads();
    for (int off = 1; off < 128; off <<= 1) {
        int v = (t >= off) ? s[t - off] : 0;
        __syncthreads();
        s[t] += v;
        __syncthreads();
    }
    if (t < nb) bsums[t] = (t == 0) ? 0 : s[t - 1];
}

__global__ __launch_bounds__(256) void scan_apply(const int* __restrict__ counts,
                                                  const int* __restrict__ bsums,
                                                  int* __restrict__ row_ptr) {
    __shared__ int s[256];
    int t = threadIdx.x;
    int base = blockIdx.x * 1024 + t * 4;
    int v[4];
    int sum = 0;
#pragma unroll
    for (int j = 0; j < 4; ++j) {
        int idx = base + j;
        v[j] = (idx < N_NODES) ? counts[idx] : 0;
        sum += v[j];
    }
    s[t] = sum;
    __syncthreads();
    for (int off = 1; off < 256; off <<= 1) {
        int a = (t >= off) ? s[t - off] : 0;
        __syncthreads();
        s[t] += a;
        __syncthreads();
    }
    int excl = ((t == 0) ? 0 : s[t - 1]) + bsums[blockIdx.x];
    int run = 0;
#pragma unroll
    for (int j = 0; j < 4; ++j) {
        int idx = base + j;
        if (idx < N_NODES) row_ptr[idx] = excl + run;
        run += v[j];
    }
    if (blockIdx.x == 0 && t == 0) row_ptr[N_NODES] = N_EDGES;
}

// ---------------- bucket fill: packed[pos] = {src, norm} ----------------
__global__ void fill_csr(const int* __restrict__ src, const int* __restrict__ dst,
                         const float* __restrict__ dinv, const int* __restrict__ row_ptr,
                         int* __restrict__ fill, int2* __restrict__ packed) {
    int e = blockIdx.x * 256 + threadIdx.x;
    if (e >= N_EDGES) return;
    int s = src[e], d = dst[e];
    int pos = row_ptr[d] + atomicAdd(&fill[d], 1);
    float norm = dinv[s] * dinv[d];
    packed[pos] = make_int2(s, __float_as_int(norm));
}

// ---------------- GEMM: Y_bf16[nrows x 128] = X[nrows x 128] @ W[128 x 128] ----------------
// 128x128 tile, 256 threads, 8x8 per thread, K chunked by 32. fp32 accumulate.
#define BM 128
#define BK 32
#define XS_STRIDE 36
template <bool BF16_IN>
__global__ __launch_bounds__(256) void gemm128(const void* __restrict__ Xv,
                                               const float* __restrict__ W,
                                               unsigned int* __restrict__ Y, int nrows) {
    __shared__ float Xs[BM * XS_STRIDE];
    __shared__ float Ws[BK * 132];
    int t = threadIdx.x;
    int tcg = t & 15;        // col group: cols tcg*8 .. +7
    int trg = t >> 4;        // row group: rows trg*8 .. +7
    int row0 = blockIdx.x * BM;

    float acc[8][8];
#pragma unroll
    for (int r = 0; r < 8; ++r)
#pragma unroll
        for (int c = 0; c < 8; ++c) acc[r][c] = 0.f;

    for (int k0 = 0; k0 < 128; k0 += BK) {
        if constexpr (BF16_IN) {
            const unsigned int* Xb = (const unsigned int*)Xv;
            for (int i = t; i < 1024; i += 256) {
                int r = i >> 3, g = i & 7;
                float4 v = make_float4(0.f, 0.f, 0.f, 0.f);
                if (row0 + r < nrows) {
                    uint2 u = *(const uint2*)&Xb[(size_t)(row0 + r) * 64 + (k0 >> 1) + 2 * g];
                    v.x = bflo(u.x); v.y = bfhi(u.x); v.z = bflo(u.y); v.w = bfhi(u.y);
                }
                int gs = (g + (r >> 3)) & 7;
                *(float4*)&Xs[r * XS_STRIDE + gs * 4] = v;
            }
        } else {
            const float* X = (const float*)Xv;
            for (int i = t; i < 1024; i += 256) {
                int r = i >> 3, g = i & 7;
                float4 v = make_float4(0.f, 0.f, 0.f, 0.f);
                if (row0 + r < nrows)
                    v = ((const float4*)X)[(size_t)(row0 + r) * 32 + (k0 >> 2) + g];
                int gs = (g + (r >> 3)) & 7;
                *(float4*)&Xs[r * XS_STRIDE + gs * 4] = v;
            }
        }
        for (int i = t; i < 1024; i += 256) {
            int kk = i >> 5, c4 = i & 31;
            *(float4*)&Ws[kk * 132 + c4 * 4] =
                ((const float4*)W)[(size_t)(k0 + kk) * 32 + c4];
        }
        __syncthreads();

#pragma unroll
        for (int kk = 0; kk < BK; kk += 4) {
            float4 xv[8];
#pragma unroll
            for (int r = 0; r < 8; ++r) {
                int gs = ((kk >> 2) + trg) & 7;
                xv[r] = *(float4*)&Xs[(trg * 8 + r) * XS_STRIDE + gs * 4];
            }
#pragma unroll
            for (int j = 0; j < 4; ++j) {
                float4 wa = *(float4*)&Ws[(kk + j) * 132 + tcg * 8];
                float4 wb = *(float4*)&Ws[(kk + j) * 132 + tcg * 8 + 4];
#pragma unroll
                for (int r = 0; r < 8; ++r) {
                    float xr = j == 0 ? xv[r].x : j == 1 ? xv[r].y : j == 2 ? xv[r].z : xv[r].w;
                    acc[r][0] = fmaf(xr, wa.x, acc[r][0]);
                    acc[r][1] = fmaf(xr, wa.y, acc[r][1]);
                    acc[r][2] = fmaf(xr, wa.z, acc[r][2]);
                    acc[r][3] = fmaf(xr, wa.w, acc[r][3]);
                    acc[r][4] = fmaf(xr, wb.x, acc[r][4]);
                    acc[r][5] = fmaf(xr, wb.y, acc[r][5]);
                    acc[r][6] = fmaf(xr, wb.z, acc[r][6]);
                    acc[r][7] = fmaf(xr, wb.w, acc[r][7]);
                }
            }
        }
        __syncthreads();
    }

#pragma unroll
    for (int r = 0; r < 8; ++r) {
        int row = row0 + trg * 8 + r;
        if (row < nrows) {
            uint4 pk;
            pk.x = bf16pack(acc[r][0], acc[r][1]);
            pk.y = bf16pack(acc[r][2], acc[r][3]);
            pk.z = bf16pack(acc[r][4], acc[r][5]);
            pk.w = bf16pack(acc[r][6], acc[r][7]);
            ((uint4*)Y)[(size_t)row * 16 + tcg] = pk;
        }
    }
}

// ---------------- gather-aggregate: one wave per node ----------------
// lane holds 2 features (1 uint). X[v] = [relu+bias](d2*H[v] + sum nrm*H[s])
template <bool RELU>
__global__ __launch_bounds__(256) void aggregate(const unsigned int* __restrict__ Hb,
                                                 const int2* __restrict__ packed,
                                                 const int* __restrict__ row_ptr,
                                                 const float* __restrict__ dinv,
                                                 const float* __restrict__ bias,
                                                 unsigned int* __restrict__ Xb) {
    int v = blockIdx.x * 4 + (threadIdx.x >> 6);
    int lane = threadIdx.x & 63;
    if (v >= N_NODES) return;
    int start = row_ptr[v];
    int end = row_ptr[v + 1];
    float dv = dinv[v];
    float d2 = dv * dv;
    unsigned int su = Hb[(size_t)v * 64 + lane];
    float a0 = d2 * bflo(su);
    float a1 = d2 * bfhi(su);
    for (int base = start; base < end; base += 64) {
        int n = end - base;
        if (n > 64) n = 64;
        int2 p = make_int2(0, 0);
        if (base + lane < end) p = packed[base + lane];
        for (int j = 0; j < n; ++j) {
            int s = __shfl(p.x, j);
            float nrm = __int_as_float(__shfl(p.y, j));
            unsigned int u = Hb[(size_t)s * 64 + lane];
            a0 = fmaf(nrm, bflo(u), a0);
            a1 = fmaf(nrm, bfhi(u), a1);
        }
    }
    if (RELU) {
        float2 b = ((const float2*)bias)[lane];
        a0 = fmaxf(a0 + b.x, 0.f);
        a1 = fmaxf(a1 + b.y, 0.f);
    }
    Xb[(size_t)v * 64 + lane] = bf16pack(a0, a1);
}

// ---------------- edge scoring: out[e] = dot(X[a]+b2, X[b]+b2) ----------------
__global__ __launch_bounds__(256) void score_kernel(const int* __restrict__ ea,
                                                    const int* __restrict__ eb,
                                                    const unsigned int* __restrict__ Xb,
                                                    const float* __restrict__ bias,
                                                    float* __restrict__ out) {
    int wid = blockIdx.x * 4 + (threadIdx.x >> 6);
    int lane = threadIdx.x & 63;
    if (wid >= N_LABEL) return;
    int ia = ea[wid], ib = eb[wid];
    float2 bb = ((const float2*)bias)[lane];
    unsigned int ua = Xb[(size_t)ia * 64 + lane];
    unsigned int ub = Xb[(size_t)ib * 64 + lane];
    float p = (bflo(ua) + bb.x) * (bflo(ub) + bb.x) + (bfhi(ua) + bb.y) * (bfhi(ub) + bb.y);
#pragma unroll
    for (int off = 32; off > 0; off >>= 1) p += __shfl_down(p, off);
    if (lane == 0) out[wid] = p;
}

extern "C" void kernel_launch(void* const* d_in, const int* in_sizes, int n_in,
                              void* d_out, int out_size, void* d_ws, size_t ws_size,
                              hipStream_t stream) {
    const float* feat = (const float*)d_in[0];
    const int* ei = (const int*)d_in[1];
    const int* eli = (const int*)d_in[2];
    const float* W1 = (const float*)d_in[3];
    const float* b1 = (const float*)d_in[4];
    const float* W2 = (const float*)d_in[5];
    const float* b2 = (const float*)d_in[6];
    float* out = (float*)d_out;

    const int* src = ei;
    const int* dst = ei + N_EDGES;
    const int* la = eli;
    const int* lb = eli + N_LABEL;

    int* counts = (int*)d_ws;                    // N
    int* fill = counts + N_NODES;                // N
    int* row_ptr = fill + N_NODES;               // N+1
    int* bsums = row_ptr + N_NODES + 1;          // 128
    float* dinv = (float*)(bsums + 128);         // N
    int2* packed = (int2*)(dinv + N_NODES + 3);  // E int2 (8 MB), 8B-aligned
    unsigned int* Hb = (unsigned int*)(packed + N_EDGES);  // N*64 uints (bf16 x128)
    unsigned int* Xb = Hb + (size_t)N_NODES * 64;          // N*64 uints

    const int TB = 256;
    int gE = (N_EDGES + TB - 1) / TB;
    int gN = (N_NODES + TB - 1) / TB;
    int gScan = (N_NODES + 1023) / 1024;
    int gGemm = (N_NODES + BM - 1) / BM;     // 782
    int gAgg = (N_NODES + 3) / 4;            // 25000 (wave per node, 4/block)
    int gScore = (N_LABEL + 3) / 4;          // 50000

    hipMemsetAsync(counts, 0, 2 * N_NODES * sizeof(int), stream);

    // CSR build
    deg_hist<<<gE, TB, 0, stream>>>(dst, counts);
    make_dinv<<<gN, TB, 0, stream>>>(counts, dinv);
    scan_reduce<<<gScan, TB, 0, stream>>>(counts, bsums);
    scan_top<<<1, 128, 0, stream>>>(bsums, gScan);
    scan_apply<<<gScan, TB, 0, stream>>>(counts, bsums, row_ptr);
    fill_csr<<<gE, TB, 0, stream>>>(src, dst, dinv, row_ptr, fill, packed);

    // layer 1: H1 = feat @ W1 (bf16 out); X1 = relu(agg(H1) + b1) (bf16)
    gemm128<false><<<gGemm, TB, 0, stream>>>(feat, W1, Hb, N_NODES);
    aggregate<true><<<gAgg, TB, 0, stream>>>(Hb, packed, row_ptr, dinv, b1, Xb);

    // layer 2: H2 = X1 @ W2 (bf16 in/out); X2 = agg(H2) (bias folded into score)
    gemm128<true><<<gGemm, TB, 0, stream>>>(Xb, W2, Hb, N_NODES);
    aggregate<false><<<gAgg, TB, 0, stream>>>(Hb, packed, row_ptr, dinv, b2, Xb);

    // scoring (b2 folded in)
    score_kernel<<<gScore, TB, 0, stream>>>(la, lb, Xb, b2, out);
}

// Round 5
// 460.136 us; speedup vs baseline: 8.0693x; 1.0856x over previous
//
#include <hip/hip_runtime.h>
#include <hip/hip_bf16.h>

// GCN link-prediction: 2x GCNConv(128->128) + edge dot scoring.
// Round 5: aggregate was latency-bound (1 gather in flight, VALUBusy 27%,
// HBM 33%). Unroll edge loop by 8 with shfl-broadcast metadata -> 8
// independent row-gathers in flight per wave.

#define N_NODES 100000
#define N_EDGES 1000000
#define N_LABEL 200000
#define D_FEAT 128

// ---- bf16 helpers (RNE) ----
__device__ inline unsigned int f2bf(float x) {
    unsigned int u = __float_as_uint(x);
    return (u + 0x7FFFu + ((u >> 16) & 1u)) >> 16;
}
__device__ inline unsigned int bf16pack(float a, float b) {
    return f2bf(a) | (f2bf(b) << 16);
}
__device__ inline float bflo(unsigned int u) { return __uint_as_float(u << 16); }
__device__ inline float bfhi(unsigned int u) { return __uint_as_float(u & 0xFFFF0000u); }

// ---------------- degree histogram (int atomics) ----------------
__global__ void deg_hist(const int* __restrict__ dst, int* __restrict__ counts) {
    int e = blockIdx.x * 256 + threadIdx.x;
    if (e < N_EDGES) atomicAdd(&counts[dst[e]], 1);
}

__global__ void make_dinv(const int* __restrict__ counts, float* __restrict__ dinv) {
    int i = blockIdx.x * 256 + threadIdx.x;
    if (i < N_NODES) dinv[i] = rsqrtf((float)(counts[i] + 1));  // +1 self-loop
}

// ---------------- exclusive scan over counts -> row_ptr ----------------
__global__ __launch_bounds__(256) void scan_reduce(const int* __restrict__ counts,
                                                   int* __restrict__ bsums) {
    __shared__ int s[256];
    int t = threadIdx.x;
    int base = blockIdx.x * 1024 + t * 4;
    int sum = 0;
#pragma unroll
    for (int j = 0; j < 4; ++j) {
        int idx = base + j;
        if (idx < N_NODES) sum += counts[idx];
    }
    s[t] = sum;
    __syncthreads();
    for (int off = 128; off > 0; off >>= 1) {
        if (t < off) s[t] += s[t + off];
        __syncthreads();
    }
    if (t == 0) bsums[blockIdx.x] = s[0];
}

__global__ void scan_top(int* __restrict__ bsums, int nb) {
    __shared__ int s[128];
    int t = threadIdx.x;
    s[t] = (t < nb) ? bsums[t] : 0;
    __syncthreads();
    for (int off = 1; off < 128; off <<= 1) {
        int v = (t >= off) ? s[t - off] : 0;
        __syncthreads();
        s[t] += v;
        __syncthreads();
    }
    if (t < nb) bsums[t] = (t == 0) ? 0 : s[t - 1];
}

__global__ __launch_bounds__(256) void scan_apply(const int* __restrict__ counts,
                                                  const int* __restrict__ bsums,
                                                  int* __restrict__ row_ptr) {
    __shared__ int s[256];
    int t = threadIdx.x;
    int base = blockIdx.x * 1024 + t * 4;
    int v[4];
    int sum = 0;
#pragma unroll
    for (int j = 0; j < 4; ++j) {
        int idx = base + j;
        v[j] = (idx < N_NODES) ? counts[idx] : 0;
        sum += v[j];
    }
    s[t] = sum;
    __syncthreads();
    for (int off = 1; off < 256; off <<= 1) {
        int a = (t >= off) ? s[t - off] : 0;
        __syncthreads();
        s[t] += a;
        __syncthreads();
    }
    int excl = ((t == 0) ? 0 : s[t - 1]) + bsums[blockIdx.x];
    int run = 0;
#pragma unroll
    for (int j = 0; j < 4; ++j) {
        int idx = base + j;
        if (idx < N_NODES) row_ptr[idx] = excl + run;
        run += v[j];
    }
    if (blockIdx.x == 0 && t == 0) row_ptr[N_NODES] = N_EDGES;
}

// ---------------- bucket fill: packed[pos] = {src, norm} ----------------
__global__ void fill_csr(const int* __restrict__ src, const int* __restrict__ dst,
                         const float* __restrict__ dinv, const int* __restrict__ row_ptr,
                         int* __restrict__ fill, int2* __restrict__ packed) {
    int e = blockIdx.x * 256 + threadIdx.x;
    if (e >= N_EDGES) return;
    int s = src[e], d = dst[e];
    int pos = row_ptr[d] + atomicAdd(&fill[d], 1);
    float norm = dinv[s] * dinv[d];
    packed[pos] = make_int2(s, __float_as_int(norm));
}

// ---------------- GEMM: Y_bf16[nrows x 128] = X[nrows x 128] @ W[128 x 128] ----------------
#define BM 128
#define BK 32
#define XS_STRIDE 36
template <bool BF16_IN>
__global__ __launch_bounds__(256) void gemm128(const void* __restrict__ Xv,
                                               const float* __restrict__ W,
                                               unsigned int* __restrict__ Y, int nrows) {
    __shared__ float Xs[BM * XS_STRIDE];
    __shared__ float Ws[BK * 132];
    int t = threadIdx.x;
    int tcg = t & 15;
    int trg = t >> 4;
    int row0 = blockIdx.x * BM;

    float acc[8][8];
#pragma unroll
    for (int r = 0; r < 8; ++r)
#pragma unroll
        for (int c = 0; c < 8; ++c) acc[r][c] = 0.f;

    for (int k0 = 0; k0 < 128; k0 += BK) {
        if constexpr (BF16_IN) {
            const unsigned int* Xb = (const unsigned int*)Xv;
            for (int i = t; i < 1024; i += 256) {
                int r = i >> 3, g = i & 7;
                float4 v = make_float4(0.f, 0.f, 0.f, 0.f);
                if (row0 + r < nrows) {
                    uint2 u = *(const uint2*)&Xb[(size_t)(row0 + r) * 64 + (k0 >> 1) + 2 * g];
                    v.x = bflo(u.x); v.y = bfhi(u.x); v.z = bflo(u.y); v.w = bfhi(u.y);
                }
                int gs = (g + (r >> 3)) & 7;
                *(float4*)&Xs[r * XS_STRIDE + gs * 4] = v;
            }
        } else {
            const float* X = (const float*)Xv;
            for (int i = t; i < 1024; i += 256) {
                int r = i >> 3, g = i & 7;
                float4 v = make_float4(0.f, 0.f, 0.f, 0.f);
                if (row0 + r < nrows)
                    v = ((const float4*)X)[(size_t)(row0 + r) * 32 + (k0 >> 2) + g];
                int gs = (g + (r >> 3)) & 7;
                *(float4*)&Xs[r * XS_STRIDE + gs * 4] = v;
            }
        }
        for (int i = t; i < 1024; i += 256) {
            int kk = i >> 5, c4 = i & 31;
            *(float4*)&Ws[kk * 132 + c4 * 4] =
                ((const float4*)W)[(size_t)(k0 + kk) * 32 + c4];
        }
        __syncthreads();

#pragma unroll
        for (int kk = 0; kk < BK; kk += 4) {
            float4 xv[8];
#pragma unroll
            for (int r = 0; r < 8; ++r) {
                int gs = ((kk >> 2) + trg) & 7;
                xv[r] = *(float4*)&Xs[(trg * 8 + r) * XS_STRIDE + gs * 4];
            }
#pragma unroll
            for (int j = 0; j < 4; ++j) {
                float4 wa = *(float4*)&Ws[(kk + j) * 132 + tcg * 8];
                float4 wb = *(float4*)&Ws[(kk + j) * 132 + tcg * 8 + 4];
#pragma unroll
                for (int r = 0; r < 8; ++r) {
                    float xr = j == 0 ? xv[r].x : j == 1 ? xv[r].y : j == 2 ? xv[r].z : xv[r].w;
                    acc[r][0] = fmaf(xr, wa.x, acc[r][0]);
                    acc[r][1] = fmaf(xr, wa.y, acc[r][1]);
                    acc[r][2] = fmaf(xr, wa.z, acc[r][2]);
                    acc[r][3] = fmaf(xr, wa.w, acc[r][3]);
                    acc[r][4] = fmaf(xr, wb.x, acc[r][4]);
                    acc[r][5] = fmaf(xr, wb.y, acc[r][5]);
                    acc[r][6] = fmaf(xr, wb.z, acc[r][6]);
                    acc[r][7] = fmaf(xr, wb.w, acc[r][7]);
                }
            }
        }
        __syncthreads();
    }

#pragma unroll
    for (int r = 0; r < 8; ++r) {
        int row = row0 + trg * 8 + r;
        if (row < nrows) {
            uint4 pk;
            pk.x = bf16pack(acc[r][0], acc[r][1]);
            pk.y = bf16pack(acc[r][2], acc[r][3]);
            pk.z = bf16pack(acc[r][4], acc[r][5]);
            pk.w = bf16pack(acc[r][6], acc[r][7]);
            ((uint4*)Y)[(size_t)row * 16 + tcg] = pk;
        }
    }
}

// ---------------- gather-aggregate: one wave per node, 8 gathers in flight ----
template <bool RELU>
__global__ __launch_bounds__(256) void aggregate(const unsigned int* __restrict__ Hb,
                                                 const int2* __restrict__ packed,
                                                 const int* __restrict__ row_ptr,
                                                 const float* __restrict__ dinv,
                                                 const float* __restrict__ bias,
                                                 unsigned int* __restrict__ Xb) {
    int v = blockIdx.x * 4 + (threadIdx.x >> 6);
    int lane = threadIdx.x & 63;
    if (v >= N_NODES) return;
    int start = row_ptr[v];
    int end = row_ptr[v + 1];
    float dv = dinv[v];
    float d2 = dv * dv;
    unsigned int su = Hb[(size_t)v * 64 + lane];
    float a0 = d2 * bflo(su);
    float a1 = d2 * bfhi(su);

    for (int base = start; base < end; base += 64) {
        int n = end - base;
        if (n > 64) n = 64;
        int2 p = make_int2(0, 0);
        if (base + lane < end) p = packed[base + lane];
        int j = 0;
        // 8-deep pipeline: 8 independent gathers in flight
        for (; j + 8 <= n; j += 8) {
            int s[8];
            float nr[8];
#pragma unroll
            for (int q = 0; q < 8; ++q) {
                s[q] = __shfl(p.x, j + q);
                nr[q] = __int_as_float(__shfl(p.y, j + q));
            }
            unsigned int u[8];
#pragma unroll
            for (int q = 0; q < 8; ++q) u[q] = Hb[(size_t)s[q] * 64 + lane];
#pragma unroll
            for (int q = 0; q < 8; ++q) {
                a0 = fmaf(nr[q], bflo(u[q]), a0);
                a1 = fmaf(nr[q], bfhi(u[q]), a1);
            }
        }
        // 4-deep for mid tail
        for (; j + 4 <= n; j += 4) {
            int s[4];
            float nr[4];
#pragma unroll
            for (int q = 0; q < 4; ++q) {
                s[q] = __shfl(p.x, j + q);
                nr[q] = __int_as_float(__shfl(p.y, j + q));
            }
            unsigned int u[4];
#pragma unroll
            for (int q = 0; q < 4; ++q) u[q] = Hb[(size_t)s[q] * 64 + lane];
#pragma unroll
            for (int q = 0; q < 4; ++q) {
                a0 = fmaf(nr[q], bflo(u[q]), a0);
                a1 = fmaf(nr[q], bfhi(u[q]), a1);
            }
        }
        for (; j < n; ++j) {
            int s = __shfl(p.x, j);
            float nrm = __int_as_float(__shfl(p.y, j));
            unsigned int u = Hb[(size_t)s * 64 + lane];
            a0 = fmaf(nrm, bflo(u), a0);
            a1 = fmaf(nrm, bfhi(u), a1);
        }
    }
    if (RELU) {
        float2 b = ((const float2*)bias)[lane];
        a0 = fmaxf(a0 + b.x, 0.f);
        a1 = fmaxf(a1 + b.y, 0.f);
    }
    Xb[(size_t)v * 64 + lane] = bf16pack(a0, a1);
}

// ---------------- edge scoring: out[e] = dot(X[a]+b2, X[b]+b2) ----------------
__global__ __launch_bounds__(256) void score_kernel(const int* __restrict__ ea,
                                                    const int* __restrict__ eb,
                                                    const unsigned int* __restrict__ Xb,
                                                    const float* __restrict__ bias,
                                                    float* __restrict__ out) {
    int wid = blockIdx.x * 4 + (threadIdx.x >> 6);
    int lane = threadIdx.x & 63;
    if (wid >= N_LABEL) return;
    int ia = ea[wid], ib = eb[wid];
    float2 bb = ((const float2*)bias)[lane];
    unsigned int ua = Xb[(size_t)ia * 64 + lane];
    unsigned int ub = Xb[(size_t)ib * 64 + lane];
    float p = (bflo(ua) + bb.x) * (bflo(ub) + bb.x) + (bfhi(ua) + bb.y) * (bfhi(ub) + bb.y);
#pragma unroll
    for (int off = 32; off > 0; off >>= 1) p += __shfl_down(p, off);
    if (lane == 0) out[wid] = p;
}

extern "C" void kernel_launch(void* const* d_in, const int* in_sizes, int n_in,
                              void* d_out, int out_size, void* d_ws, size_t ws_size,
                              hipStream_t stream) {
    const float* feat = (const float*)d_in[0];
    const int* ei = (const int*)d_in[1];
    const int* eli = (const int*)d_in[2];
    const float* W1 = (const float*)d_in[3];
    const float* b1 = (const float*)d_in[4];
    const float* W2 = (const float*)d_in[5];
    const float* b2 = (const float*)d_in[6];
    float* out = (float*)d_out;

    const int* src = ei;
    const int* dst = ei + N_EDGES;
    const int* la = eli;
    const int* lb = eli + N_LABEL;

    int* counts = (int*)d_ws;                    // N
    int* fill = counts + N_NODES;                // N
    int* row_ptr = fill + N_NODES;               // N+1
    int* bsums = row_ptr + N_NODES + 1;          // 128
    float* dinv = (float*)(bsums + 128);         // N
    int2* packed = (int2*)(dinv + N_NODES + 3);  // E int2 (8 MB)
    unsigned int* Hb = (unsigned int*)(packed + N_EDGES);  // N*64 uints
    unsigned int* Xb = Hb + (size_t)N_NODES * 64;          // N*64 uints

    const int TB = 256;
    int gE = (N_EDGES + TB - 1) / TB;
    int gN = (N_NODES + TB - 1) / TB;
    int gScan = (N_NODES + 1023) / 1024;
    int gGemm = (N_NODES + BM - 1) / BM;
    int gAgg = (N_NODES + 3) / 4;
    int gScore = (N_LABEL + 3) / 4;

    hipMemsetAsync(counts, 0, 2 * N_NODES * sizeof(int), stream);

    // CSR build
    deg_hist<<<gE, TB, 0, stream>>>(dst, counts);
    make_dinv<<<gN, TB, 0, stream>>>(counts, dinv);
    scan_reduce<<<gScan, TB, 0, stream>>>(counts, bsums);
    scan_top<<<1, 128, 0, stream>>>(bsums, gScan);
    scan_apply<<<gScan, TB, 0, stream>>>(counts, bsums, row_ptr);
    fill_csr<<<gE, TB, 0, stream>>>(src, dst, dinv, row_ptr, fill, packed);

    // layer 1
    gemm128<false><<<gGemm, TB, 0, stream>>>(feat, W1, Hb, N_NODES);
    aggregate<true><<<gAgg, TB, 0, stream>>>(Hb, packed, row_ptr, dinv, b1, Xb);

    // layer 2
    gemm128<true><<<gGemm, TB, 0, stream>>>(Xb, W2, Hb, N_NODES);
    aggregate<false><<<gAgg, TB, 0, stream>>>(Hb, packed, row_ptr, dinv, b2, Xb);

    // scoring (b2 folded in)
    score_kernel<<<gScore, TB, 0, stream>>>(la, lb, Xb, b2, out);
}

// Round 6
// 368.839 us; speedup vs baseline: 10.0666x; 1.2475x over previous
//
#include <hip/hip_runtime.h>
#include <hip/hip_bf16.h>

// GCN link-prediction: 2x GCNConv(128->128) + edge dot scoring.
// Round 6: MFMA bf16 GEMM (old fp32-VALU gemm was LDS-throughput-bound with a
// 4-way bank conflict on W reads: 3.2M conflict cycles). W staged transposed
// in LDS as bf16 with chunk-XOR swizzle; A-frags direct from global.

#define N_NODES 100000
#define N_EDGES 1000000
#define N_LABEL 200000
#define D_FEAT 128
#define BM 128

typedef short bf16x8 __attribute__((ext_vector_type(8)));
typedef float f32x4 __attribute__((ext_vector_type(4)));

// ---- bf16 helpers (RNE) ----
__device__ inline unsigned int f2bf(float x) {
    unsigned int u = __float_as_uint(x);
    return (u + 0x7FFFu + ((u >> 16) & 1u)) >> 16;
}
__device__ inline unsigned int bf16pack(float a, float b) {
    return f2bf(a) | (f2bf(b) << 16);
}
__device__ inline float bflo(unsigned int u) { return __uint_as_float(u << 16); }
__device__ inline float bfhi(unsigned int u) { return __uint_as_float(u & 0xFFFF0000u); }

// ---------------- degree histogram (int atomics) ----------------
__global__ void deg_hist(const int* __restrict__ dst, int* __restrict__ counts) {
    int e = blockIdx.x * 256 + threadIdx.x;
    if (e < N_EDGES) atomicAdd(&counts[dst[e]], 1);
}

__global__ void make_dinv(const int* __restrict__ counts, float* __restrict__ dinv) {
    int i = blockIdx.x * 256 + threadIdx.x;
    if (i < N_NODES) dinv[i] = rsqrtf((float)(counts[i] + 1));  // +1 self-loop
}

// ---------------- exclusive scan over counts -> row_ptr ----------------
__global__ __launch_bounds__(256) void scan_reduce(const int* __restrict__ counts,
                                                   int* __restrict__ bsums) {
    __shared__ int s[256];
    int t = threadIdx.x;
    int base = blockIdx.x * 1024 + t * 4;
    int sum = 0;
#pragma unroll
    for (int j = 0; j < 4; ++j) {
        int idx = base + j;
        if (idx < N_NODES) sum += counts[idx];
    }
    s[t] = sum;
    __syncthreads();
    for (int off = 128; off > 0; off >>= 1) {
        if (t < off) s[t] += s[t + off];
        __syncthreads();
    }
    if (t == 0) bsums[blockIdx.x] = s[0];
}

__global__ void scan_top(int* __restrict__ bsums, int nb) {
    __shared__ int s[128];
    int t = threadIdx.x;
    s[t] = (t < nb) ? bsums[t] : 0;
    __syncthreads();
    for (int off = 1; off < 128; off <<= 1) {
        int v = (t >= off) ? s[t - off] : 0;
        __syncthreads();
        s[t] += v;
        __syncthreads();
    }
    if (t < nb) bsums[t] = (t == 0) ? 0 : s[t - 1];
}

__global__ __launch_bounds__(256) void scan_apply(const int* __restrict__ counts,
                                                  const int* __restrict__ bsums,
                                                  int* __restrict__ row_ptr) {
    __shared__ int s[256];
    int t = threadIdx.x;
    int base = blockIdx.x * 1024 + t * 4;
    int v[4];
    int sum = 0;
#pragma unroll
    for (int j = 0; j < 4; ++j) {
        int idx = base + j;
        v[j] = (idx < N_NODES) ? counts[idx] : 0;
        sum += v[j];
    }
    s[t] = sum;
    __syncthreads();
    for (int off = 1; off < 256; off <<= 1) {
        int a = (t >= off) ? s[t - off] : 0;
        __syncthreads();
        s[t] += a;
        __syncthreads();
    }
    int excl = ((t == 0) ? 0 : s[t - 1]) + bsums[blockIdx.x];
    int run = 0;
#pragma unroll
    for (int j = 0; j < 4; ++j) {
        int idx = base + j;
        if (idx < N_NODES) row_ptr[idx] = excl + run;
        run += v[j];
    }
    if (blockIdx.x == 0 && t == 0) row_ptr[N_NODES] = N_EDGES;
}

// ---------------- bucket fill: packed[pos] = {src, norm} ----------------
__global__ void fill_csr(const int* __restrict__ src, const int* __restrict__ dst,
                         const float* __restrict__ dinv, const int* __restrict__ row_ptr,
                         int* __restrict__ fill, int2* __restrict__ packed) {
    int e = blockIdx.x * 256 + threadIdx.x;
    if (e >= N_EDGES) return;
    int s = src[e], d = dst[e];
    int pos = row_ptr[d] + atomicAdd(&fill[d], 1);
    float norm = dinv[s] * dinv[d];
    packed[pos] = make_int2(s, __float_as_int(norm));
}

// ---------------- MFMA GEMM: Y_bf16[nrows x 128] = X[nrows x 128] @ W[128 x 128] ----
// Block: 128 rows x 128 cols, 4 waves; wave: 32 rows x 128 cols = 2x8 16x16 tiles.
// W staged in LDS as bf16, transposed (Wt[n][k]) in 16B chunks; chunk (n,q)
// (q = k/8) stored at slot (q ^ (n&15)) within row n -> B-frag b128 reads hit
// bank groups uniformly (2-way max = free).
template <bool BF16_IN>
__global__ __launch_bounds__(256) void gemm128_mfma(const void* __restrict__ Xv,
                                                    const float* __restrict__ W,
                                                    unsigned int* __restrict__ Y,
                                                    int nrows) {
    __shared__ short Wt[128 * 128];  // 32 KB
    int t = threadIdx.x;

    // stage W: fp32 -> bf16, transposed + swizzled. 2048 chunks / 256 threads.
#pragma unroll
    for (int i = 0; i < 8; ++i) {
        int c = i * 256 + t;
        int n = c & 127, q = c >> 7;
        float w[8];
#pragma unroll
        for (int j = 0; j < 8; ++j) w[j] = W[(size_t)(q * 8 + j) * 128 + n];
        union { uint4 u; bf16x8 v; } pk;
        pk.u.x = bf16pack(w[0], w[1]);
        pk.u.y = bf16pack(w[2], w[3]);
        pk.u.z = bf16pack(w[4], w[5]);
        pk.u.w = bf16pack(w[6], w[7]);
        *(bf16x8*)&Wt[n * 128 + ((q ^ (n & 15)) << 3)] = pk.v;
    }
    __syncthreads();

    int wv = t >> 6;
    int lane = t & 63, l16 = lane & 15, quad = lane >> 4;
    int rbase = blockIdx.x * BM + wv * 32;

    f32x4 acc[2][8];
#pragma unroll
    for (int rt = 0; rt < 2; ++rt)
#pragma unroll
        for (int nt = 0; nt < 8; ++nt) acc[rt][nt] = (f32x4){0.f, 0.f, 0.f, 0.f};

#pragma unroll
    for (int kb = 0; kb < 4; ++kb) {  // k0 = kb*32
        bf16x8 af[2];
#pragma unroll
        for (int rt = 0; rt < 2; ++rt) {
            int row = rbase + rt * 16 + l16;
            if (row > nrows - 1) row = nrows - 1;  // clamp; result discarded at store
            if constexpr (BF16_IN) {
                const unsigned int* Xb = (const unsigned int*)Xv;
                af[rt] = *(const bf16x8*)&Xb[(size_t)row * 64 + kb * 16 + quad * 4];
            } else {
                const float* X = (const float*)Xv;
                float4 fa = ((const float4*)X)[(size_t)row * 32 + kb * 8 + quad * 2];
                float4 fb = ((const float4*)X)[(size_t)row * 32 + kb * 8 + quad * 2 + 1];
                union { uint4 u; bf16x8 v; } cv;
                cv.u.x = bf16pack(fa.x, fa.y);
                cv.u.y = bf16pack(fa.z, fa.w);
                cv.u.z = bf16pack(fb.x, fb.y);
                cv.u.w = bf16pack(fb.z, fb.w);
                af[rt] = cv.v;
            }
        }
        bf16x8 bfr[8];
#pragma unroll
        for (int nt = 0; nt < 8; ++nt) {
            int n = nt * 16 + l16;
            bfr[nt] = *(const bf16x8*)&Wt[n * 128 + (((kb * 4 + quad) ^ l16) << 3)];
        }
#pragma unroll
        for (int rt = 0; rt < 2; ++rt)
#pragma unroll
            for (int nt = 0; nt < 8; ++nt)
                acc[rt][nt] = __builtin_amdgcn_mfma_f32_16x16x32_bf16(
                    af[rt], bfr[nt], acc[rt][nt], 0, 0, 0);
    }

    // epilogue: C/D layout col=lane&15, row=quad*4+reg
    short* Ys = (short*)Y;
#pragma unroll
    for (int rt = 0; rt < 2; ++rt) {
#pragma unroll
        for (int reg = 0; reg < 4; ++reg) {
            int row = rbase + rt * 16 + quad * 4 + reg;
            if (row < nrows) {
#pragma unroll
                for (int nt = 0; nt < 8; ++nt)
                    Ys[(size_t)row * 128 + nt * 16 + l16] = (short)f2bf(acc[rt][nt][reg]);
            }
        }
    }
}

// ---------------- gather-aggregate: one wave per node, 8 gathers in flight ----
template <bool RELU>
__global__ __launch_bounds__(256) void aggregate(const unsigned int* __restrict__ Hb,
                                                 const int2* __restrict__ packed,
                                                 const int* __restrict__ row_ptr,
                                                 const float* __restrict__ dinv,
                                                 const float* __restrict__ bias,
                                                 unsigned int* __restrict__ Xb) {
    int v = blockIdx.x * 4 + (threadIdx.x >> 6);
    int lane = threadIdx.x & 63;
    if (v >= N_NODES) return;
    int start = row_ptr[v];
    int end = row_ptr[v + 1];
    float dv = dinv[v];
    float d2 = dv * dv;
    unsigned int su = Hb[(size_t)v * 64 + lane];
    float a0 = d2 * bflo(su);
    float a1 = d2 * bfhi(su);

    for (int base = start; base < end; base += 64) {
        int n = end - base;
        if (n > 64) n = 64;
        int2 p = make_int2(0, 0);
        if (base + lane < end) p = packed[base + lane];
        int j = 0;
        for (; j + 8 <= n; j += 8) {
            int s[8];
            float nr[8];
#pragma unroll
            for (int q = 0; q < 8; ++q) {
                s[q] = __shfl(p.x, j + q);
                nr[q] = __int_as_float(__shfl(p.y, j + q));
            }
            unsigned int u[8];
#pragma unroll
            for (int q = 0; q < 8; ++q) u[q] = Hb[(size_t)s[q] * 64 + lane];
#pragma unroll
            for (int q = 0; q < 8; ++q) {
                a0 = fmaf(nr[q], bflo(u[q]), a0);
                a1 = fmaf(nr[q], bfhi(u[q]), a1);
            }
        }
        for (; j + 4 <= n; j += 4) {
            int s[4];
            float nr[4];
#pragma unroll
            for (int q = 0; q < 4; ++q) {
                s[q] = __shfl(p.x, j + q);
                nr[q] = __int_as_float(__shfl(p.y, j + q));
            }
            unsigned int u[4];
#pragma unroll
            for (int q = 0; q < 4; ++q) u[q] = Hb[(size_t)s[q] * 64 + lane];
#pragma unroll
            for (int q = 0; q < 4; ++q) {
                a0 = fmaf(nr[q], bflo(u[q]), a0);
                a1 = fmaf(nr[q], bfhi(u[q]), a1);
            }
        }
        for (; j < n; ++j) {
            int s = __shfl(p.x, j);
            float nrm = __int_as_float(__shfl(p.y, j));
            unsigned int u = Hb[(size_t)s * 64 + lane];
            a0 = fmaf(nrm, bflo(u), a0);
            a1 = fmaf(nrm, bfhi(u), a1);
        }
    }
    if (RELU) {
        float2 b = ((const float2*)bias)[lane];
        a0 = fmaxf(a0 + b.x, 0.f);
        a1 = fmaxf(a1 + b.y, 0.f);
    }
    Xb[(size_t)v * 64 + lane] = bf16pack(a0, a1);
}

// ---------------- edge scoring: out[e] = dot(X[a]+b2, X[b]+b2) ----------------
__global__ __launch_bounds__(256) void score_kernel(const int* __restrict__ ea,
                                                    const int* __restrict__ eb,
                                                    const unsigned int* __restrict__ Xb,
                                                    const float* __restrict__ bias,
                                                    float* __restrict__ out) {
    int wid = blockIdx.x * 4 + (threadIdx.x >> 6);
    int lane = threadIdx.x & 63;
    if (wid >= N_LABEL) return;
    int ia = ea[wid], ib = eb[wid];
    float2 bb = ((const float2*)bias)[lane];
    unsigned int ua = Xb[(size_t)ia * 64 + lane];
    unsigned int ub = Xb[(size_t)ib * 64 + lane];
    float p = (bflo(ua) + bb.x) * (bflo(ub) + bb.x) + (bfhi(ua) + bb.y) * (bfhi(ub) + bb.y);
#pragma unroll
    for (int off = 32; off > 0; off >>= 1) p += __shfl_down(p, off);
    if (lane == 0) out[wid] = p;
}

extern "C" void kernel_launch(void* const* d_in, const int* in_sizes, int n_in,
                              void* d_out, int out_size, void* d_ws, size_t ws_size,
                              hipStream_t stream) {
    const float* feat = (const float*)d_in[0];
    const int* ei = (const int*)d_in[1];
    const int* eli = (const int*)d_in[2];
    const float* W1 = (const float*)d_in[3];
    const float* b1 = (const float*)d_in[4];
    const float* W2 = (const float*)d_in[5];
    const float* b2 = (const float*)d_in[6];
    float* out = (float*)d_out;

    const int* src = ei;
    const int* dst = ei + N_EDGES;
    const int* la = eli;
    const int* lb = eli + N_LABEL;

    int* counts = (int*)d_ws;                    // N
    int* fill = counts + N_NODES;                // N
    int* row_ptr = fill + N_NODES;               // N+1
    int* bsums = row_ptr + N_NODES + 1;          // 128
    float* dinv = (float*)(bsums + 128);         // N
    int2* packed = (int2*)(dinv + N_NODES + 3);  // E int2 (8 MB)
    unsigned int* Hb = (unsigned int*)(packed + N_EDGES);  // N*64 uints
    unsigned int* Xb = Hb + (size_t)N_NODES * 64;          // N*64 uints

    const int TB = 256;
    int gE = (N_EDGES + TB - 1) / TB;
    int gN = (N_NODES + TB - 1) / TB;
    int gScan = (N_NODES + 1023) / 1024;
    int gGemm = (N_NODES + BM - 1) / BM;
    int gAgg = (N_NODES + 3) / 4;
    int gScore = (N_LABEL + 3) / 4;

    hipMemsetAsync(counts, 0, 2 * N_NODES * sizeof(int), stream);

    // CSR build
    deg_hist<<<gE, TB, 0, stream>>>(dst, counts);
    make_dinv<<<gN, TB, 0, stream>>>(counts, dinv);
    scan_reduce<<<gScan, TB, 0, stream>>>(counts, bsums);
    scan_top<<<1, 128, 0, stream>>>(bsums, gScan);
    scan_apply<<<gScan, TB, 0, stream>>>(counts, bsums, row_ptr);
    fill_csr<<<gE, TB, 0, stream>>>(src, dst, dinv, row_ptr, fill, packed);

    // layer 1
    gemm128_mfma<false><<<gGemm, TB, 0, stream>>>(feat, W1, Hb, N_NODES);
    aggregate<true><<<gAgg, TB, 0, stream>>>(Hb, packed, row_ptr, dinv, b1, Xb);

    // layer 2
    gemm128_mfma<true><<<gGemm, TB, 0, stream>>>(Xb, W2, Hb, N_NODES);
    aggregate<false><<<gAgg, TB, 0, stream>>>(Hb, packed, row_ptr, dinv, b2, Xb);

    // scoring (b2 folded in)
    score_kernel<<<gScore, TB, 0, stream>>>(la, lb, Xb, b2, out);
}